// Round 6
// baseline (407.943 us; speedup 1.0000x reference)
//
#include <hip/hip_runtime.h>
#include <hip/hip_bf16.h>

#define D 128
#define N0_ 1048576
#define N1_ 131072
#define N2_ 8192
#define E0_ 1048576
#define E1_ 131072

#define CONVB 3584
#define HISTB 512

typedef float f32x4 __attribute__((ext_vector_type(4)));
typedef short bf16x8 __attribute__((ext_vector_type(8)));
typedef unsigned short u16x4 __attribute__((ext_vector_type(4)));

__device__ __forceinline__ short f2bf(float f) {
    __hip_bfloat16 h = __float2bfloat16(f);
    return __builtin_bit_cast(short, h);
}
__device__ __forceinline__ float bf2f(short s) {
    return __bfloat162float(__builtin_bit_cast(__hip_bfloat16, s));
}

// ---------------- zero joint degree array ----------------
__global__ __launch_bounds__(256) void zero_kernel(int4* __restrict__ p, int n4) {
    int i = blockIdx.x * 256 + threadIdx.x;
    if (i < n4) p[i] = int4{0, 0, 0, 0};
}

// ---------------- fused: x->bf16 conversion (blocks < CONVB) || histogram ----
__global__ __launch_bounds__(256) void conv_hist(
    const f32x4* __restrict__ x4, u16x4* __restrict__ xbf4,
    const int* __restrict__ dst0, const int* __restrict__ dst1,
    int* __restrict__ deg) {
    if (blockIdx.x < CONVB) {
        const int n4 = N0_ * D / 4;  // 33,554,432
        for (int i = blockIdx.x * 256 + threadIdx.x; i < n4; i += CONVB * 256) {
            f32x4 v = x4[i];
            u16x4 o;
            o[0] = (unsigned short)f2bf(v[0]);
            o[1] = (unsigned short)f2bf(v[1]);
            o[2] = (unsigned short)f2bf(v[2]);
            o[3] = (unsigned short)f2bf(v[3]);
            xbf4[i] = o;
        }
    } else {
        const int nq0 = E0_ / 4, nq = (E0_ + E1_) / 4;
        for (int g = (blockIdx.x - CONVB) * 256 + threadIdx.x; g < nq;
             g += HISTB * 256) {
            if (g < nq0) {
                int4 d4 = ((const int4*)dst0)[g];
                atomicAdd(&deg[d4.x], 1);
                atomicAdd(&deg[d4.y], 1);
                atomicAdd(&deg[d4.z], 1);
                atomicAdd(&deg[d4.w], 1);
            } else {
                int4 d4 = ((const int4*)dst1)[g - nq0];
                atomicAdd(&deg[N1_ + d4.x], 1);
                atomicAdd(&deg[N1_ + d4.y], 1);
                atomicAdd(&deg[N1_ + d4.z], 1);
                atomicAdd(&deg[N1_ + d4.w], 1);
            }
        }
    }
}

// ---------------- 3-phase exclusive scan ----------------
__global__ __launch_bounds__(256) void scan1(const int* __restrict__ deg,
                                             int* __restrict__ offs,
                                             int* __restrict__ bsum, int n) {
    __shared__ int ws[4];
    int i = blockIdx.x * 256 + threadIdx.x;
    int lane = threadIdx.x & 63, wid = threadIdx.x >> 6;
    int v = (i < n) ? deg[i] : 0;
    int incl = v;
#pragma unroll
    for (int d = 1; d < 64; d <<= 1) {
        int u = __shfl_up(incl, d);
        if (lane >= d) incl += u;
    }
    if (lane == 63) ws[wid] = incl;
    __syncthreads();
    if (threadIdx.x == 0) {
        int a = 0;
        for (int w = 0; w < 4; ++w) { int t = ws[w]; ws[w] = a; a += t; }
        bsum[blockIdx.x] = a;
    }
    __syncthreads();
    if (i < n) offs[i] = incl - v + ws[wid];
}

__global__ __launch_bounds__(1024) void scan2(int* __restrict__ bsum, int nb) {
    __shared__ int ws[16];
    int i = threadIdx.x, lane = i & 63, wid = i >> 6;
    int v = (i < nb) ? bsum[i] : 0;
    int incl = v;
#pragma unroll
    for (int d = 1; d < 64; d <<= 1) {
        int u = __shfl_up(incl, d);
        if (lane >= d) incl += u;
    }
    if (lane == 63) ws[wid] = incl;
    __syncthreads();
    if (i == 0) {
        int a = 0;
        for (int w = 0; w < 16; ++w) { int t = ws[w]; ws[w] = a; a += t; }
    }
    __syncthreads();
    if (i < nb) bsum[i] = incl - v + ws[wid];
}

__global__ __launch_bounds__(256) void scan3(int* __restrict__ offs,
                                             const int* __restrict__ bsum, int n) {
    int i = blockIdx.x * 256 + threadIdx.x;
    if (i < n) offs[i] += bsum[blockIdx.x];
}

// ---------------- joint edge scatter (mutates offs -> segment ends) ----------
__global__ __launch_bounds__(256) void scatter_both(const int* __restrict__ src0,
                                                    const int* __restrict__ dst0,
                                                    const int* __restrict__ src1,
                                                    const int* __restrict__ dst1,
                                                    int* __restrict__ offs,
                                                    int* __restrict__ eidx0,
                                                    int* __restrict__ eidx1) {
    int g = blockIdx.x * 256 + threadIdx.x;  // quad index
    if (g < E0_ / 4) {
        int4 s4 = ((const int4*)src0)[g];
        int4 d4 = ((const int4*)dst0)[g];
        int p;
        p = atomicAdd(&offs[d4.x], 1); eidx0[p] = s4.x;
        p = atomicAdd(&offs[d4.y], 1); eidx0[p] = s4.y;
        p = atomicAdd(&offs[d4.z], 1); eidx0[p] = s4.z;
        p = atomicAdd(&offs[d4.w], 1); eidx0[p] = s4.w;
    } else {
        int gq = g - E0_ / 4;
        int4 s4 = ((const int4*)src1)[gq];
        int4 d4 = ((const int4*)dst1)[gq];
        int p;
        p = atomicAdd(&offs[N1_ + d4.x], 1); eidx1[p - E0_] = s4.x;
        p = atomicAdd(&offs[N1_ + d4.y], 1); eidx1[p - E0_] = s4.y;
        p = atomicAdd(&offs[N1_ + d4.z], 1); eidx1[p - E0_] = s4.z;
        p = atomicAdd(&offs[N1_ + d4.w], 1); eidx1[p - E0_] = s4.w;
    }
}

// ---------------- gather helper: bf16 row, 8B per lane, 32 lanes/row ----------
__device__ __forceinline__ f32x4 row_load4(const short* xs, int s, int hl) {
    u16x4 v = ((const u16x4*)(xs + (size_t)s * D))[hl];
    f32x4 r;
    r[0] = bf2f((short)v[0]); r[1] = bf2f((short)v[1]);
    r[2] = bf2f((short)v[2]); r[3] = bf2f((short)v[3]);
    return r;
}

// ---------------- aggregate: one wave per target, 2 rows per pass ----------
__global__ __launch_bounds__(256) void aggregate(const short* __restrict__ xsrc,
                                                 const int* __restrict__ eidx,
                                                 const int* __restrict__ offs_end,
                                                 const int* __restrict__ deg,
                                                 int joint_base, int eidx_sub,
                                                 short* __restrict__ mean, int ntgt) {
    const int lane = threadIdx.x & 63;
    const int half = lane >> 5, hl = lane & 31;
    const int gw = (blockIdx.x * 256 + threadIdx.x) >> 6;
    const int nw = (gridDim.x * 256) >> 6;
    for (int t = gw; t < ntgt; t += nw) {
        const int tj = joint_base + t;
        const int dgr = deg[tj];
        const int start = offs_end[tj] - dgr - eidx_sub;
        f32x4 acc = {0.0f, 0.0f, 0.0f, 0.0f};
        for (int base = 0; base < dgr; base += 64) {
            const int nc = min(64, dgr - base);
            int sidx = (lane < nc) ? eidx[start + base + lane] : 0;
            int i = 0;
            for (; i + 8 <= nc; i += 8) {  // 8 edges in flight
                f32x4 v[4];
#pragma unroll
                for (int u = 0; u < 4; ++u) {
                    int s0 = __shfl(sidx, i + 2 * u);
                    int s1 = __shfl(sidx, i + 2 * u + 1);
                    v[u] = row_load4(xsrc, half ? s1 : s0, hl);
                }
#pragma unroll
                for (int u = 0; u < 4; ++u) acc += v[u];
            }
            for (; i + 2 <= nc; i += 2) {
                int s0 = __shfl(sidx, i);
                int s1 = __shfl(sidx, i + 1);
                acc += row_load4(xsrc, half ? s1 : s0, hl);
            }
            if (i < nc) {
                int s0 = __shfl(sidx, i);
                if (half == 0) acc += row_load4(xsrc, s0, hl);
            }
        }
#pragma unroll
        for (int c = 0; c < 4; ++c) acc[c] += __shfl_xor(acc[c], 32);
        const float r = (dgr > 0) ? 1.0f / (float)dgr : 0.0f;
        if (half == 0) {
            u16x4 o;
#pragma unroll
            for (int c = 0; c < 4; ++c) o[c] = (unsigned short)f2bf(acc[c] * r);
            ((u16x4*)(mean + (size_t)t * D))[hl] = o;
        }
    }
}

// ---------------- fused node update (all-bf16 A operands) ----------------
// out[n] = relu( [mean | x_tgt] @ vstack(Wl,Wr) + bl )
template <bool OUTBF16>
__global__ __launch_bounds__(256) void sage_update(
    const short* __restrict__ mean, const short* __restrict__ xtgt,
    const float* __restrict__ Wl, const float* __restrict__ Wr,
    const float* __restrict__ bl, void* __restrict__ out_v, int ntiles) {
    __shared__ __align__(16) char wt[128 * 256 * 2];  // WT[j][kk] bf16, 64KB

    {
        int t = threadIdx.x;
        int j = t & 127;
        int half = t >> 7;  // 0 -> Wl, 1 -> Wr
        const float* W = half ? Wr : Wl;
        for (int k = 0; k < 128; ++k) {
            float v = W[k * 128 + j];  // coalesced over j
            int kk = half * 128 + k;
            int byte = (j * 512 + kk * 2) ^ ((j & 7) << 4);
            *reinterpret_cast<short*>(wt + byte) = f2bf(v);
        }
    }
    __syncthreads();

    const int wave = threadIdx.x >> 6, lane = threadIdx.x & 63;
    const int rl = lane & 15;
    const int kq = lane >> 4;

    float blv[8];
#pragma unroll
    for (int nt = 0; nt < 8; ++nt) blv[nt] = bl[nt * 16 + rl];

    for (int tile = blockIdx.x; tile < ntiles; tile += gridDim.x) {
        const int grow = tile * 64 + wave * 16 + rl;
        f32x4 acc[8] = {};

#pragma unroll
        for (int ks = 0; ks < 8; ++ks) {
            const int k0 = ks * 32 + kq * 8;
            bf16x8 af;
            if (ks < 4) {
                af = *reinterpret_cast<const bf16x8*>(mean + (size_t)grow * D + k0);
            } else {
                af = *reinterpret_cast<const bf16x8*>(xtgt + (size_t)grow * D + k0 - 128);
            }
#pragma unroll
            for (int nt = 0; nt < 8; ++nt) {
                const int j = nt * 16 + rl;
                const int byte = (j * 512 + k0 * 2) ^ ((j & 7) << 4);
                bf16x8 bfr = *reinterpret_cast<const bf16x8*>(wt + byte);
                acc[nt] =
                    __builtin_amdgcn_mfma_f32_16x16x32_bf16(af, bfr, acc[nt], 0, 0, 0);
            }
        }

        const int orow_base = tile * 64 + wave * 16 + kq * 4;
#pragma unroll
        for (int nt = 0; nt < 8; ++nt) {
            const int col = nt * 16 + rl;
#pragma unroll
            for (int r = 0; r < 4; ++r) {
                float v = acc[nt][r] + blv[nt];
                v = fmaxf(v, 0.0f);
                const size_t idx = (size_t)(orow_base + r) * D + col;
                if (OUTBF16)
                    ((short*)out_v)[idx] = f2bf(v);
                else
                    ((float*)out_v)[idx] = v;
            }
        }
    }
}

extern "C" void kernel_launch(void* const* d_in, const int* in_sizes, int n_in,
                              void* d_out, int out_size, void* d_ws, size_t ws_size,
                              hipStream_t stream) {
    const float* x   = (const float*)d_in[0];
    const float* Wl0 = (const float*)d_in[1];
    const float* bl0 = (const float*)d_in[2];
    const float* Wr0 = (const float*)d_in[3];
    const float* Wl1 = (const float*)d_in[4];
    const float* bl1 = (const float*)d_in[5];
    const float* Wr1 = (const float*)d_in[6];
    const int* src0  = (const int*)d_in[7];
    const int* dst0  = (const int*)d_in[8];
    const int* src1  = (const int*)d_in[9];
    const int* dst1  = (const int*)d_in[10];

    char* ws = (char*)d_ws;
    int*   deg   = (int*)(ws);                 // 557056 B (N1+N2 ints)
    int*   offs  = (int*)(ws + 557056);        // 557056 B
    int*   bsum  = (int*)(ws + 1114112);       // 4096 B (544 used)
    int*   eidx0 = (int*)(ws + 1118208);       // 4 MB
    int*   eidx1 = (int*)(ws + 5312512);       // 512 KB
    short* mean0 = (short*)(ws + 5836800);     // 32 MB
    short* mean1 = (short*)(ws + 39391232);    // 2 MB
    short* h     = (short*)(ws + 41488384);    // 32 MB
    short* xbf   = (short*)(ws + 75042816);    // 256 MB bf16 copy of x

    const int NJ = N1_ + N2_;  // 139264

    // zero joint deg
    zero_kernel<<<136, 256, 0, stream>>>((int4*)deg, NJ / 4);
    // fused x->bf16 conversion || joint histogram
    conv_hist<<<CONVB + HISTB, 256, 0, stream>>>(
        (const f32x4*)x, (u16x4*)xbf, dst0, dst1, deg);
    // joint exclusive scan
    scan1<<<NJ / 256, 256, 0, stream>>>(deg, offs, bsum, NJ);
    scan2<<<1, 1024, 0, stream>>>(bsum, NJ / 256);
    scan3<<<NJ / 256, 256, 0, stream>>>(offs, bsum, NJ);
    // joint edge scatter (offs -> segment ends)
    scatter_both<<<(E0_ + E1_) / 1024, 256, 0, stream>>>(src0, dst0, src1, dst1,
                                                         offs, eidx0, eidx1);

    // layer 0 (gather from L3-resident bf16 pool)
    aggregate<<<4096, 256, 0, stream>>>(xbf, eidx0, offs, deg, 0, 0, mean0, N1_);
    sage_update<true><<<1024, 256, 0, stream>>>(
        mean0, xbf, Wl0, Wr0, bl0, h, N1_ / 64);

    // layer 1
    aggregate<<<2048, 256, 0, stream>>>(h, eidx1, offs, deg, N1_, E0_, mean1, N2_);
    sage_update<false><<<128, 256, 0, stream>>>(
        mean1, h, Wl1, Wr1, bl1, d_out, N2_ / 64);
}

// Round 7
// 328.861 us; speedup vs baseline: 1.2405x; 1.2405x over previous
//
#include <hip/hip_runtime.h>
#include <hip/hip_bf16.h>

#define D 128
#define N0_ 1048576
#define N1_ 131072
#define N2_ 8192
#define E0_ 1048576
#define E1_ 131072

#define NCONV 512  // conversion blocks inside agg0_conv

typedef float f32x4 __attribute__((ext_vector_type(4)));
typedef short bf16x8 __attribute__((ext_vector_type(8)));
typedef unsigned short u16x4 __attribute__((ext_vector_type(4)));

__device__ __forceinline__ short f2bf(float f) {
    __hip_bfloat16 h = __float2bfloat16(f);
    return __builtin_bit_cast(short, h);
}
__device__ __forceinline__ float bf2f(short s) {
    return __bfloat162float(__builtin_bit_cast(__hip_bfloat16, s));
}

// ---------------- zero joint degree array ----------------
__global__ __launch_bounds__(256) void zero_kernel(int4* __restrict__ p, int n4) {
    int i = blockIdx.x * 256 + threadIdx.x;
    if (i < n4) p[i] = int4{0, 0, 0, 0};
}

// ---------------- joint histogram ----------------
__global__ __launch_bounds__(256) void hist_both(const int* __restrict__ dst0,
                                                 const int* __restrict__ dst1,
                                                 int* __restrict__ deg) {
    int g = blockIdx.x * 256 + threadIdx.x;  // quad index
    if (g < E0_ / 4) {
        int4 d4 = ((const int4*)dst0)[g];
        atomicAdd(&deg[d4.x], 1);
        atomicAdd(&deg[d4.y], 1);
        atomicAdd(&deg[d4.z], 1);
        atomicAdd(&deg[d4.w], 1);
    } else {
        int4 d4 = ((const int4*)dst1)[g - E0_ / 4];
        atomicAdd(&deg[N1_ + d4.x], 1);
        atomicAdd(&deg[N1_ + d4.y], 1);
        atomicAdd(&deg[N1_ + d4.z], 1);
        atomicAdd(&deg[N1_ + d4.w], 1);
    }
}

// ---------------- 3-phase exclusive scan ----------------
__global__ __launch_bounds__(256) void scan1(const int* __restrict__ deg,
                                             int* __restrict__ offs,
                                             int* __restrict__ bsum, int n) {
    __shared__ int ws[4];
    int i = blockIdx.x * 256 + threadIdx.x;
    int lane = threadIdx.x & 63, wid = threadIdx.x >> 6;
    int v = (i < n) ? deg[i] : 0;
    int incl = v;
#pragma unroll
    for (int d = 1; d < 64; d <<= 1) {
        int u = __shfl_up(incl, d);
        if (lane >= d) incl += u;
    }
    if (lane == 63) ws[wid] = incl;
    __syncthreads();
    if (threadIdx.x == 0) {
        int a = 0;
        for (int w = 0; w < 4; ++w) { int t = ws[w]; ws[w] = a; a += t; }
        bsum[blockIdx.x] = a;
    }
    __syncthreads();
    if (i < n) offs[i] = incl - v + ws[wid];
}

__global__ __launch_bounds__(1024) void scan2(int* __restrict__ bsum, int nb) {
    __shared__ int ws[16];
    int i = threadIdx.x, lane = i & 63, wid = i >> 6;
    int v = (i < nb) ? bsum[i] : 0;
    int incl = v;
#pragma unroll
    for (int d = 1; d < 64; d <<= 1) {
        int u = __shfl_up(incl, d);
        if (lane >= d) incl += u;
    }
    if (lane == 63) ws[wid] = incl;
    __syncthreads();
    if (i == 0) {
        int a = 0;
        for (int w = 0; w < 16; ++w) { int t = ws[w]; ws[w] = a; a += t; }
    }
    __syncthreads();
    if (i < nb) bsum[i] = incl - v + ws[wid];
}

__global__ __launch_bounds__(256) void scan3(int* __restrict__ offs,
                                             const int* __restrict__ bsum, int n) {
    int i = blockIdx.x * 256 + threadIdx.x;
    if (i < n) offs[i] += bsum[blockIdx.x];
}

// ---------------- joint edge scatter (mutates offs -> segment ends) ----------
__global__ __launch_bounds__(256) void scatter_both(const int* __restrict__ src0,
                                                    const int* __restrict__ dst0,
                                                    const int* __restrict__ src1,
                                                    const int* __restrict__ dst1,
                                                    int* __restrict__ offs,
                                                    int* __restrict__ eidx0,
                                                    int* __restrict__ eidx1) {
    int g = blockIdx.x * 256 + threadIdx.x;  // quad index
    if (g < E0_ / 4) {
        int4 s4 = ((const int4*)src0)[g];
        int4 d4 = ((const int4*)dst0)[g];
        int p;
        p = atomicAdd(&offs[d4.x], 1); eidx0[p] = s4.x;
        p = atomicAdd(&offs[d4.y], 1); eidx0[p] = s4.y;
        p = atomicAdd(&offs[d4.z], 1); eidx0[p] = s4.z;
        p = atomicAdd(&offs[d4.w], 1); eidx0[p] = s4.w;
    } else {
        int gq = g - E0_ / 4;
        int4 s4 = ((const int4*)src1)[gq];
        int4 d4 = ((const int4*)dst1)[gq];
        int p;
        p = atomicAdd(&offs[N1_ + d4.x], 1); eidx1[p - E0_] = s4.x;
        p = atomicAdd(&offs[N1_ + d4.y], 1); eidx1[p - E0_] = s4.y;
        p = atomicAdd(&offs[N1_ + d4.z], 1); eidx1[p - E0_] = s4.z;
        p = atomicAdd(&offs[N1_ + d4.w], 1); eidx1[p - E0_] = s4.w;
    }
}

// ---------------- gather helpers: 32 lanes per row ----------
__device__ __forceinline__ f32x4 row_load_f32(const float* xs, int s, int hl) {
    return ((const f32x4*)(xs + (size_t)s * D))[hl];
}
__device__ __forceinline__ f32x4 row_load_bf16(const short* xs, int s, int hl) {
    u16x4 v = ((const u16x4*)(xs + (size_t)s * D))[hl];
    f32x4 r;
    r[0] = bf2f((short)v[0]); r[1] = bf2f((short)v[1]);
    r[2] = bf2f((short)v[2]); r[3] = bf2f((short)v[3]);
    return r;
}

// ---------------- layer-0 aggregate (fp32 src) fused with x->bf16 conv ------
// blocks [0, NCONV): convert x[0:N1] to bf16 (96 MB streaming, hides under
// the gather's spare BW). blocks [NCONV, ...): one wave per target gather.
__global__ __launch_bounds__(256) void agg0_conv(
    const float* __restrict__ x, const int* __restrict__ eidx,
    const int* __restrict__ offs_end, const int* __restrict__ deg,
    short* __restrict__ mean, short* __restrict__ xtgt_bf) {
    if (blockIdx.x < NCONV) {
        const f32x4* x4 = (const f32x4*)x;
        u16x4* o4 = (u16x4*)xtgt_bf;
        const int n4 = N1_ * D / 4;  // 4,194,304
        for (int i = blockIdx.x * 256 + threadIdx.x; i < n4; i += NCONV * 256) {
            f32x4 v = x4[i];
            u16x4 o;
            o[0] = (unsigned short)f2bf(v[0]);
            o[1] = (unsigned short)f2bf(v[1]);
            o[2] = (unsigned short)f2bf(v[2]);
            o[3] = (unsigned short)f2bf(v[3]);
            o4[i] = o;
        }
        return;
    }
    const int lane = threadIdx.x & 63;
    const int half = lane >> 5, hl = lane & 31;
    const int gw = ((blockIdx.x - NCONV) * 256 + threadIdx.x) >> 6;
    const int nw = ((gridDim.x - NCONV) * 256) >> 6;
    for (int t = gw; t < N1_; t += nw) {
        const int dgr = deg[t];
        const int start = offs_end[t] - dgr;
        f32x4 acc = {0.0f, 0.0f, 0.0f, 0.0f};
        for (int base = 0; base < dgr; base += 64) {
            const int nc = min(64, dgr - base);
            int sidx = (lane < nc) ? eidx[start + base + lane] : 0;
            int i = 0;
            for (; i + 8 <= nc; i += 8) {  // 8 rows in flight
                f32x4 v[4];
#pragma unroll
                for (int u = 0; u < 4; ++u) {
                    int s0 = __shfl(sidx, i + 2 * u);
                    int s1 = __shfl(sidx, i + 2 * u + 1);
                    v[u] = row_load_f32(x, half ? s1 : s0, hl);
                }
#pragma unroll
                for (int u = 0; u < 4; ++u) acc += v[u];
            }
            for (; i + 2 <= nc; i += 2) {
                int s0 = __shfl(sidx, i);
                int s1 = __shfl(sidx, i + 1);
                acc += row_load_f32(x, half ? s1 : s0, hl);
            }
            if (i < nc) {
                int s0 = __shfl(sidx, i);
                if (half == 0) acc += row_load_f32(x, s0, hl);
            }
        }
#pragma unroll
        for (int c = 0; c < 4; ++c) acc[c] += __shfl_xor(acc[c], 32);
        const float r = (dgr > 0) ? 1.0f / (float)dgr : 0.0f;
        if (half == 0) {
            u16x4 o;
#pragma unroll
            for (int c = 0; c < 4; ++c) o[c] = (unsigned short)f2bf(acc[c] * r);
            ((u16x4*)(mean + (size_t)t * D))[hl] = o;
        }
    }
}

// ---------------- layer-1 aggregate (bf16 src) ----------
__global__ __launch_bounds__(256) void aggregate1(const short* __restrict__ xsrc,
                                                  const int* __restrict__ eidx,
                                                  const int* __restrict__ offs_end,
                                                  const int* __restrict__ deg,
                                                  short* __restrict__ mean) {
    const int lane = threadIdx.x & 63;
    const int half = lane >> 5, hl = lane & 31;
    const int gw = (blockIdx.x * 256 + threadIdx.x) >> 6;
    const int nw = (gridDim.x * 256) >> 6;
    for (int t = gw; t < N2_; t += nw) {
        const int tj = N1_ + t;
        const int dgr = deg[tj];
        const int start = offs_end[tj] - dgr - E0_;
        f32x4 acc = {0.0f, 0.0f, 0.0f, 0.0f};
        for (int base = 0; base < dgr; base += 64) {
            const int nc = min(64, dgr - base);
            int sidx = (lane < nc) ? eidx[start + base + lane] : 0;
            int i = 0;
            for (; i + 8 <= nc; i += 8) {
                f32x4 v[4];
#pragma unroll
                for (int u = 0; u < 4; ++u) {
                    int s0 = __shfl(sidx, i + 2 * u);
                    int s1 = __shfl(sidx, i + 2 * u + 1);
                    v[u] = row_load_bf16(xsrc, half ? s1 : s0, hl);
                }
#pragma unroll
                for (int u = 0; u < 4; ++u) acc += v[u];
            }
            for (; i + 2 <= nc; i += 2) {
                int s0 = __shfl(sidx, i);
                int s1 = __shfl(sidx, i + 1);
                acc += row_load_bf16(xsrc, half ? s1 : s0, hl);
            }
            if (i < nc) {
                int s0 = __shfl(sidx, i);
                if (half == 0) acc += row_load_bf16(xsrc, s0, hl);
            }
        }
#pragma unroll
        for (int c = 0; c < 4; ++c) acc[c] += __shfl_xor(acc[c], 32);
        const float r = (dgr > 0) ? 1.0f / (float)dgr : 0.0f;
        if (half == 0) {
            u16x4 o;
#pragma unroll
            for (int c = 0; c < 4; ++c) o[c] = (unsigned short)f2bf(acc[c] * r);
            ((u16x4*)(mean + (size_t)t * D))[hl] = o;
        }
    }
}

// ---------------- fused node update (all-bf16 A operands) ----------------
// out[n] = relu( [mean | x_tgt] @ vstack(Wl,Wr) + bl )
template <bool OUTBF16>
__global__ __launch_bounds__(256) void sage_update(
    const short* __restrict__ mean, const short* __restrict__ xtgt,
    const float* __restrict__ Wl, const float* __restrict__ Wr,
    const float* __restrict__ bl, void* __restrict__ out_v, int ntiles) {
    __shared__ __align__(16) char wt[128 * 256 * 2];  // WT[j][kk] bf16, 64KB

    {
        int t = threadIdx.x;
        int j = t & 127;
        int half = t >> 7;  // 0 -> Wl, 1 -> Wr
        const float* W = half ? Wr : Wl;
        for (int k = 0; k < 128; ++k) {
            float v = W[k * 128 + j];  // coalesced over j
            int kk = half * 128 + k;
            int byte = (j * 512 + kk * 2) ^ ((j & 7) << 4);
            *reinterpret_cast<short*>(wt + byte) = f2bf(v);
        }
    }
    __syncthreads();

    const int wave = threadIdx.x >> 6, lane = threadIdx.x & 63;
    const int rl = lane & 15;
    const int kq = lane >> 4;

    float blv[8];
#pragma unroll
    for (int nt = 0; nt < 8; ++nt) blv[nt] = bl[nt * 16 + rl];

    for (int tile = blockIdx.x; tile < ntiles; tile += gridDim.x) {
        const int grow = tile * 64 + wave * 16 + rl;
        f32x4 acc[8] = {};

#pragma unroll
        for (int ks = 0; ks < 8; ++ks) {
            const int k0 = ks * 32 + kq * 8;
            bf16x8 af;
            if (ks < 4) {
                af = *reinterpret_cast<const bf16x8*>(mean + (size_t)grow * D + k0);
            } else {
                af = *reinterpret_cast<const bf16x8*>(xtgt + (size_t)grow * D + k0 - 128);
            }
#pragma unroll
            for (int nt = 0; nt < 8; ++nt) {
                const int j = nt * 16 + rl;
                const int byte = (j * 512 + k0 * 2) ^ ((j & 7) << 4);
                bf16x8 bfr = *reinterpret_cast<const bf16x8*>(wt + byte);
                acc[nt] =
                    __builtin_amdgcn_mfma_f32_16x16x32_bf16(af, bfr, acc[nt], 0, 0, 0);
            }
        }

        const int orow_base = tile * 64 + wave * 16 + kq * 4;
#pragma unroll
        for (int nt = 0; nt < 8; ++nt) {
            const int col = nt * 16 + rl;
#pragma unroll
            for (int r = 0; r < 4; ++r) {
                float v = acc[nt][r] + blv[nt];
                v = fmaxf(v, 0.0f);
                const size_t idx = (size_t)(orow_base + r) * D + col;
                if (OUTBF16)
                    ((short*)out_v)[idx] = f2bf(v);
                else
                    ((float*)out_v)[idx] = v;
            }
        }
    }
}

extern "C" void kernel_launch(void* const* d_in, const int* in_sizes, int n_in,
                              void* d_out, int out_size, void* d_ws, size_t ws_size,
                              hipStream_t stream) {
    const float* x   = (const float*)d_in[0];
    const float* Wl0 = (const float*)d_in[1];
    const float* bl0 = (const float*)d_in[2];
    const float* Wr0 = (const float*)d_in[3];
    const float* Wl1 = (const float*)d_in[4];
    const float* bl1 = (const float*)d_in[5];
    const float* Wr1 = (const float*)d_in[6];
    const int* src0  = (const int*)d_in[7];
    const int* dst0  = (const int*)d_in[8];
    const int* src1  = (const int*)d_in[9];
    const int* dst1  = (const int*)d_in[10];

    char* ws = (char*)d_ws;
    int*   deg     = (int*)(ws);               // 557056 B (N1+N2 ints)
    int*   offs    = (int*)(ws + 557056);      // 557056 B
    int*   bsum    = (int*)(ws + 1114112);     // 4096 B (544 used)
    int*   eidx0   = (int*)(ws + 1118208);     // 4 MB
    int*   eidx1   = (int*)(ws + 5312512);     // 512 KB
    short* mean0   = (short*)(ws + 5836800);   // 32 MB
    short* mean1   = (short*)(ws + 39391232);  // 2 MB
    short* h       = (short*)(ws + 41488384);  // 32 MB
    short* xtgt_bf = (short*)(ws + 75042816);  // 32 MB bf16 copy of x[0:N1]

    const int NJ = N1_ + N2_;  // 139264

    // joint CSR build
    zero_kernel<<<136, 256, 0, stream>>>((int4*)deg, NJ / 4);
    hist_both<<<(E0_ + E1_) / 1024, 256, 0, stream>>>(dst0, dst1, deg);
    scan1<<<NJ / 256, 256, 0, stream>>>(deg, offs, bsum, NJ);
    scan2<<<1, 1024, 0, stream>>>(bsum, NJ / 256);
    scan3<<<NJ / 256, 256, 0, stream>>>(offs, bsum, NJ);
    scatter_both<<<(E0_ + E1_) / 1024, 256, 0, stream>>>(src0, dst0, src1, dst1,
                                                         offs, eidx0, eidx1);

    // layer 0: gather (fp32 x) fused with x[0:N1]->bf16 conversion
    agg0_conv<<<NCONV + 4096, 256, 0, stream>>>(x, eidx0, offs, deg, mean0, xtgt_bf);
    sage_update<true><<<1024, 256, 0, stream>>>(
        mean0, xtgt_bf, Wl0, Wr0, bl0, h, N1_ / 64);

    // layer 1
    aggregate1<<<2048, 256, 0, stream>>>(h, eidx1, offs, deg, mean1);
    sage_update<false><<<128, 256, 0, stream>>>(
        mean1, h, Wl1, Wr1, bl1, d_out, N2_ / 64);
}

// Round 8
// 318.232 us; speedup vs baseline: 1.2819x; 1.0334x over previous
//
#include <hip/hip_runtime.h>
#include <hip/hip_bf16.h>

#define D 128
#define N0_ 1048576
#define N1_ 131072
#define N2_ 8192
#define E0_ 1048576
#define E1_ 131072

typedef float f32x4 __attribute__((ext_vector_type(4)));
typedef short bf16x8 __attribute__((ext_vector_type(8)));
typedef unsigned short u16x4 __attribute__((ext_vector_type(4)));

__device__ __forceinline__ short f2bf(float f) {
    __hip_bfloat16 h = __float2bfloat16(f);
    return __builtin_bit_cast(short, h);
}
__device__ __forceinline__ float bf2f(short s) {
    return __bfloat162float(__builtin_bit_cast(__hip_bfloat16, s));
}

// ---------------- joint histogram ----------------
__global__ __launch_bounds__(256) void hist_both(const int* __restrict__ dst0,
                                                 const int* __restrict__ dst1,
                                                 int* __restrict__ deg) {
    int g = blockIdx.x * 256 + threadIdx.x;  // quad index
    if (g < E0_ / 4) {
        int4 d4 = ((const int4*)dst0)[g];
        atomicAdd(&deg[d4.x], 1);
        atomicAdd(&deg[d4.y], 1);
        atomicAdd(&deg[d4.z], 1);
        atomicAdd(&deg[d4.w], 1);
    } else {
        int4 d4 = ((const int4*)dst1)[g - E0_ / 4];
        atomicAdd(&deg[N1_ + d4.x], 1);
        atomicAdd(&deg[N1_ + d4.y], 1);
        atomicAdd(&deg[N1_ + d4.z], 1);
        atomicAdd(&deg[N1_ + d4.w], 1);
    }
}

// ---------------- 2-phase exclusive scan (chunk=256) ----------------
__global__ __launch_bounds__(256) void scan1(const int* __restrict__ deg,
                                             int* __restrict__ offs,
                                             int* __restrict__ bsum, int n) {
    __shared__ int ws[4];
    int i = blockIdx.x * 256 + threadIdx.x;
    int lane = threadIdx.x & 63, wid = threadIdx.x >> 6;
    int v = (i < n) ? deg[i] : 0;
    int incl = v;
#pragma unroll
    for (int d = 1; d < 64; d <<= 1) {
        int u = __shfl_up(incl, d);
        if (lane >= d) incl += u;
    }
    if (lane == 63) ws[wid] = incl;
    __syncthreads();
    if (threadIdx.x == 0) {
        int a = 0;
        for (int w = 0; w < 4; ++w) { int t = ws[w]; ws[w] = a; a += t; }
        bsum[blockIdx.x] = a;
    }
    __syncthreads();
    if (i < n) offs[i] = incl - v + ws[wid];  // chunk-local exclusive
}

__global__ __launch_bounds__(1024) void scan2(int* __restrict__ bsum, int nb) {
    __shared__ int ws[16];
    int i = threadIdx.x, lane = i & 63, wid = i >> 6;
    int v = (i < nb) ? bsum[i] : 0;
    int incl = v;
#pragma unroll
    for (int d = 1; d < 64; d <<= 1) {
        int u = __shfl_up(incl, d);
        if (lane >= d) incl += u;
    }
    if (lane == 63) ws[wid] = incl;
    __syncthreads();
    if (i == 0) {
        int a = 0;
        for (int w = 0; w < 16; ++w) { int t = ws[w]; ws[w] = a; a += t; }
    }
    __syncthreads();
    if (i < nb) bsum[i] = incl - v + ws[wid];  // exclusive chunk bases
}

// ---------------- joint edge scatter (offs stays chunk-local; global pos =
// chunk-local cursor + bsum[chunk]) ----------
__global__ __launch_bounds__(256) void scatter_both(const int* __restrict__ src0,
                                                    const int* __restrict__ dst0,
                                                    const int* __restrict__ src1,
                                                    const int* __restrict__ dst1,
                                                    int* __restrict__ offs,
                                                    const int* __restrict__ bsum,
                                                    int* __restrict__ eidx0,
                                                    int* __restrict__ eidx1) {
    int g = blockIdx.x * 256 + threadIdx.x;  // quad index
    if (g < E0_ / 4) {
        int4 s4 = ((const int4*)src0)[g];
        int4 d4 = ((const int4*)dst0)[g];
        int p;
        p = atomicAdd(&offs[d4.x], 1) + bsum[d4.x >> 8]; eidx0[p] = s4.x;
        p = atomicAdd(&offs[d4.y], 1) + bsum[d4.y >> 8]; eidx0[p] = s4.y;
        p = atomicAdd(&offs[d4.z], 1) + bsum[d4.z >> 8]; eidx0[p] = s4.z;
        p = atomicAdd(&offs[d4.w], 1) + bsum[d4.w >> 8]; eidx0[p] = s4.w;
    } else {
        int gq = g - E0_ / 4;
        int4 s4 = ((const int4*)src1)[gq];
        int4 d4 = ((const int4*)dst1)[gq];
        int j, p;
        j = N1_ + d4.x; p = atomicAdd(&offs[j], 1) + bsum[j >> 8]; eidx1[p - E0_] = s4.x;
        j = N1_ + d4.y; p = atomicAdd(&offs[j], 1) + bsum[j >> 8]; eidx1[p - E0_] = s4.y;
        j = N1_ + d4.z; p = atomicAdd(&offs[j], 1) + bsum[j >> 8]; eidx1[p - E0_] = s4.z;
        j = N1_ + d4.w; p = atomicAdd(&offs[j], 1) + bsum[j >> 8]; eidx1[p - E0_] = s4.w;
    }
}

// ---------------- gather helper: 32 lanes per row ----------
template <bool SRCBF16>
__device__ __forceinline__ f32x4 row_load4(const void* xsrc_v, int s, int hl) {
    if (SRCBF16) {
        const short* xs = (const short*)xsrc_v;
        u16x4 v = ((const u16x4*)(xs + (size_t)s * D))[hl];
        f32x4 r;
        r[0] = bf2f((short)v[0]); r[1] = bf2f((short)v[1]);
        r[2] = bf2f((short)v[2]); r[3] = bf2f((short)v[3]);
        return r;
    } else {
        const float* xs = (const float*)xsrc_v;
        return ((const f32x4*)(xs + (size_t)s * D))[hl];
    }
}

// ---------------- aggregate: one HALF-WAVE per target, 8 rows in flight ----
// offs holds post-scatter chunk-local cursors (= chunk-local end); global
// start = offs[tj] - deg[tj] + bsum[tj>>8] - eidx_sub.
template <bool SRCBF16>
__global__ __launch_bounds__(256) void aggregate(const void* __restrict__ xsrc_v,
                                                 const int* __restrict__ eidx,
                                                 const int* __restrict__ offs,
                                                 const int* __restrict__ deg,
                                                 const int* __restrict__ bsum,
                                                 int joint_base, int eidx_sub,
                                                 short* __restrict__ mean, int ntgt) {
    const int lane = threadIdx.x & 63;
    const int hl = lane & 31;
    const int hsel = lane & 32;  // half-wave selector for shfl broadcasts
    const int ghw = (blockIdx.x * 256 + threadIdx.x) >> 5;
    const int nhw = (gridDim.x * 256) >> 5;
    for (int t = ghw; t < ntgt; t += nhw) {
        const int tj = joint_base + t;
        const int dgr = deg[tj];
        const int start = offs[tj] - dgr + bsum[tj >> 8] - eidx_sub;
        f32x4 acc = {0.0f, 0.0f, 0.0f, 0.0f};
        for (int base = 0; base < dgr; base += 32) {
            const int nc = min(32, dgr - base);
            int sidx = (hl < nc) ? eidx[start + base + hl] : 0;
            int i = 0;
            for (; i + 8 <= nc; i += 8) {  // 8 rows in flight per half-wave
                f32x4 v[8];
#pragma unroll
                for (int u = 0; u < 8; ++u) {
                    int s = __shfl(sidx, hsel + i + u);
                    v[u] = row_load4<SRCBF16>(xsrc_v, s, hl);
                }
#pragma unroll
                for (int u = 0; u < 8; ++u) acc += v[u];
            }
            for (; i + 2 <= nc; i += 2) {
                int s0 = __shfl(sidx, hsel + i);
                int s1 = __shfl(sidx, hsel + i + 1);
                f32x4 v0 = row_load4<SRCBF16>(xsrc_v, s0, hl);
                f32x4 v1 = row_load4<SRCBF16>(xsrc_v, s1, hl);
                acc += v0;
                acc += v1;
            }
            if (i < nc) {
                int s0 = __shfl(sidx, hsel + i);
                acc += row_load4<SRCBF16>(xsrc_v, s0, hl);
            }
        }
        const float r = (dgr > 0) ? 1.0f / (float)dgr : 0.0f;
        u16x4 o;
#pragma unroll
        for (int c = 0; c < 4; ++c) o[c] = (unsigned short)f2bf(acc[c] * r);
        ((u16x4*)(mean + (size_t)t * D))[hl] = o;
    }
}

// ---------------- fused node update ----------------
// out[n] = relu( [mean(bf16) | x_tgt] @ vstack(Wl,Wr) + bl )
template <bool XBF16, bool OUTBF16>
__global__ __launch_bounds__(256) void sage_update(
    const short* __restrict__ mean, const void* __restrict__ xtgt_v,
    const float* __restrict__ Wl, const float* __restrict__ Wr,
    const float* __restrict__ bl, void* __restrict__ out_v, int ntiles) {
    __shared__ __align__(16) char wt[128 * 256 * 2];  // WT[j][kk] bf16, 64KB

    {
        int t = threadIdx.x;
        int j = t & 127;
        int half = t >> 7;  // 0 -> Wl, 1 -> Wr
        const float* W = half ? Wr : Wl;
        for (int k = 0; k < 128; ++k) {
            float v = W[k * 128 + j];  // coalesced over j
            int kk = half * 128 + k;
            int byte = (j * 512 + kk * 2) ^ ((j & 7) << 4);
            *reinterpret_cast<short*>(wt + byte) = f2bf(v);
        }
    }
    __syncthreads();

    const int wave = threadIdx.x >> 6, lane = threadIdx.x & 63;
    const int rl = lane & 15;
    const int kq = lane >> 4;

    float blv[8];
#pragma unroll
    for (int nt = 0; nt < 8; ++nt) blv[nt] = bl[nt * 16 + rl];

    for (int tile = blockIdx.x; tile < ntiles; tile += gridDim.x) {
        const int grow = tile * 64 + wave * 16 + rl;
        f32x4 acc[8] = {};

#pragma unroll
        for (int ks = 0; ks < 8; ++ks) {
            const int k0 = ks * 32 + kq * 8;
            bf16x8 af;
            if (ks < 4) {
                af = *reinterpret_cast<const bf16x8*>(mean + (size_t)grow * D + k0);
            } else {
                const int kx = k0 - 128;
                if (XBF16) {
                    af = *reinterpret_cast<const bf16x8*>(
                        (const short*)xtgt_v + (size_t)grow * D + kx);
                } else {
                    const float4* p = reinterpret_cast<const float4*>(
                        (const float*)xtgt_v + (size_t)grow * D + kx);
                    float4 a = p[0], b = p[1];
                    af[0] = f2bf(a.x); af[1] = f2bf(a.y);
                    af[2] = f2bf(a.z); af[3] = f2bf(a.w);
                    af[4] = f2bf(b.x); af[5] = f2bf(b.y);
                    af[6] = f2bf(b.z); af[7] = f2bf(b.w);
                }
            }
#pragma unroll
            for (int nt = 0; nt < 8; ++nt) {
                const int j = nt * 16 + rl;
                const int byte = (j * 512 + k0 * 2) ^ ((j & 7) << 4);
                bf16x8 bfr = *reinterpret_cast<const bf16x8*>(wt + byte);
                acc[nt] =
                    __builtin_amdgcn_mfma_f32_16x16x32_bf16(af, bfr, acc[nt], 0, 0, 0);
            }
        }

        const int orow_base = tile * 64 + wave * 16 + kq * 4;
#pragma unroll
        for (int nt = 0; nt < 8; ++nt) {
            const int col = nt * 16 + rl;
#pragma unroll
            for (int r = 0; r < 4; ++r) {
                float v = acc[nt][r] + blv[nt];
                v = fmaxf(v, 0.0f);
                const size_t idx = (size_t)(orow_base + r) * D + col;
                if (OUTBF16)
                    ((short*)out_v)[idx] = f2bf(v);
                else
                    ((float*)out_v)[idx] = v;
            }
        }
    }
}

extern "C" void kernel_launch(void* const* d_in, const int* in_sizes, int n_in,
                              void* d_out, int out_size, void* d_ws, size_t ws_size,
                              hipStream_t stream) {
    const float* x   = (const float*)d_in[0];
    const float* Wl0 = (const float*)d_in[1];
    const float* bl0 = (const float*)d_in[2];
    const float* Wr0 = (const float*)d_in[3];
    const float* Wl1 = (const float*)d_in[4];
    const float* bl1 = (const float*)d_in[5];
    const float* Wr1 = (const float*)d_in[6];
    const int* src0  = (const int*)d_in[7];
    const int* dst0  = (const int*)d_in[8];
    const int* src1  = (const int*)d_in[9];
    const int* dst1  = (const int*)d_in[10];

    char* ws = (char*)d_ws;
    int*   deg   = (int*)(ws);                 // 557056 B (N1+N2 ints)
    int*   offs  = (int*)(ws + 557056);        // 557056 B
    int*   bsum  = (int*)(ws + 1114112);       // 4096 B (544 used)
    int*   eidx0 = (int*)(ws + 1118208);       // 4 MB
    int*   eidx1 = (int*)(ws + 5312512);       // 512 KB
    short* mean0 = (short*)(ws + 5836800);     // 32 MB
    short* mean1 = (short*)(ws + 39391232);    // 2 MB
    short* h     = (short*)(ws + 41488384);    // 32 MB

    const int NJ = N1_ + N2_;  // 139264

    // joint CSR build (9 graph nodes total)
    hipMemsetAsync(deg, 0, 557056, stream);
    hist_both<<<(E0_ + E1_) / 1024, 256, 0, stream>>>(dst0, dst1, deg);
    scan1<<<NJ / 256, 256, 0, stream>>>(deg, offs, bsum, NJ);
    scan2<<<1, 1024, 0, stream>>>(bsum, NJ / 256);
    scatter_both<<<(E0_ + E1_) / 1024, 256, 0, stream>>>(src0, dst0, src1, dst1,
                                                         offs, bsum, eidx0, eidx1);

    // layer 0
    aggregate<false><<<4096, 256, 0, stream>>>(x, eidx0, offs, deg, bsum, 0, 0,
                                               mean0, N1_);
    sage_update<false, true><<<1024, 256, 0, stream>>>(
        mean0, x, Wl0, Wr0, bl0, h, N1_ / 64);

    // layer 1
    aggregate<true><<<1024, 256, 0, stream>>>(h, eidx1, offs, deg, bsum, N1_, E0_,
                                              mean1, N2_);
    sage_update<true, false><<<128, 256, 0, stream>>>(
        mean1, h, Wl1, Wr1, bl1, d_out, N2_ / 64);
}